// Round 9
// baseline (395.708 us; speedup 1.0000x reference)
//
#include <hip/hip_runtime.h>

#define NB 256   // batch
#define NS 256   // seq len == number of steps
#define NE 2     // encoder dim
#define ND 128   // decoder dim
#define NT 1024  // threads per block (16 waves, 4/SIMD)
#define NN 16    // Chebyshev nodes/degree for the h -> context map
#define RING 32  // h-history ring depth (2 store chunks of 16)
#define SLOT 144 // padded words per fp32 ring slot (4 slices of 36)
#define SLOTH 192 // padded halfs per f16 ring slot (8 slices of 24: bases 12q%32 banks, disjoint)

typedef float vf4 __attribute__((ext_vector_type(4)));
typedef _Float16 f16x2 __attribute__((ext_vector_type(2)));

constexpr float L2E = 1.4426950408889634f;  // log2(e)
constexpr float PI_F = 3.14159265358979323846f;

// Monomial coefficients of Chebyshev T_k: T_k(h) = sum_m CT[k][m] h^m (exact ints).
__device__ const float CT[16][16] = {
 {1,0,0,0,0,0,0,0,0,0,0,0,0,0,0,0},
 {0,1,0,0,0,0,0,0,0,0,0,0,0,0,0,0},
 {-1,0,2,0,0,0,0,0,0,0,0,0,0,0,0,0},
 {0,-3,0,4,0,0,0,0,0,0,0,0,0,0,0,0},
 {1,0,-8,0,8,0,0,0,0,0,0,0,0,0,0,0},
 {0,5,0,-20,0,16,0,0,0,0,0,0,0,0,0,0},
 {-1,0,18,0,-48,0,32,0,0,0,0,0,0,0,0,0},
 {0,-7,0,56,0,-112,0,64,0,0,0,0,0,0,0,0},
 {1,0,-32,0,160,0,-256,0,128,0,0,0,0,0,0,0},
 {0,9,0,-120,0,432,0,-576,0,256,0,0,0,0,0,0},
 {-1,0,50,0,-400,0,1120,0,-1280,0,512,0,0,0,0,0},
 {0,-11,0,220,0,-1232,0,2816,0,-2816,0,1024,0,0,0,0},
 {1,0,-72,0,840,0,-3584,0,6912,0,-6144,0,2048,0,0,0},
 {0,13,0,-364,0,2912,0,-9984,0,16640,0,-13312,0,4096,0,0},
 {-1,0,98,0,-1568,0,9408,0,-26880,0,39424,0,-28672,0,8192,0},
 {0,-15,0,560,0,-6048,0,28800,0,-70400,0,92160,0,-61440,0,16384}};

// DPP add: x + dpp_move(x). All-VALU cross-lane (no LDS pipe, no lgkmcnt).
template <int C>
__device__ __forceinline__ float dppadd(float x) {
    return x + __builtin_bit_cast(float,
        __builtin_amdgcn_update_dpp(0, __builtin_bit_cast(int, x), C, 0xF, 0xF, true));
}
__device__ __forceinline__ float red_oct(float x) {       // sum over each octet, all lanes
    x = dppadd<0xB1>(x); x = dppadd<0x4E>(x); x = dppadd<0x141>(x); return x;
}
__device__ __forceinline__ float red_row16(float x) {     // sum over each row of 16, all lanes
    x = dppadd<0xB1>(x); x = dppadd<0x4E>(x); x = dppadd<0x141>(x);
    x = dppadd<0x140>(x); return x;
}
__device__ __forceinline__ float red_wave64(float x) {    // valid in lane 63
    x = dppadd<0xB1>(x); x = dppadd<0x4E>(x); x = dppadd<0x141>(x);
    x = dppadd<0x140>(x); x = dppadd<0x142>(x); x = dppadd<0x143>(x); return x;
}
__device__ __forceinline__ float red_oct2wave(float x) {  // octets hold identical copies:
    // mirror/bcasts add ONE copy per octet => EXACT sum of the wave's 8 octet
    // values (same proof as R6 red_grp16, one level up), valid in lane 63.
    x = dppadd<0x140>(x); x = dppadd<0x142>(x); x = dppadd<0x143>(x); return x;
}

// One block (1024 thr, 16 waves = 4/SIMD) per batch element; 256-step
// recurrence in-block, ONE barrier per step. Attention collapsed (setup) to a
// degree-15 monomial poly, 8-way octet-split. Gate matvec in f16 fdot2:
// thread (g=t>>3, q=t&7) owns rows {g+128j} x K-slice [16q,16q+16).
__global__ __launch_bounds__(NT, 4)
void attn_lstm_decoder(const float* __restrict__ enc,   // [B,S,E]
                       const float* __restrict__ W1w,   // [S,S]
                       const float* __restrict__ W1b,   // [S]
                       const float* __restrict__ W2w,   // [S,2S]
                       const float* __restrict__ W2b,   // [S]
                       const float* __restrict__ Wih,   // [4D,E]
                       const float* __restrict__ Whh,   // [4D,D]
                       const float* __restrict__ bih,   // [4D]
                       const float* __restrict__ bhh,   // [4D]
                       float* __restrict__ out)         // [S,B,D]
{
    const int b    = blockIdx.x;
    const int t    = threadIdx.x;
    const int wave = t >> 6;
    const int lane = t & 63;
    const int g    = t >> 3;          // d-index / row group, 0..127
    const int q    = t & 7;           // K-slice eighth / monomial residue
    const bool qb0 = q & 1;
    const bool qb1 = q & 2;
    const bool qb2 = q & 4;

    __shared__ __align__(16) float    hist[RING * SLOT];    // fp32 h ring (output)
    __shared__ __align__(16) _Float16 hist16[RING * SLOTH]; // f16 h ring (dots)
    __shared__ __align__(16) float xwbuf[2][32];        // 16 waves x float2 partial x
    __shared__ float A2_l[NS];
    __shared__ float g2_l[NS];
    __shared__ float e0_l[NS];
    __shared__ float e1_l[NS];
    __shared__ float Ml[NN * NN];
    __shared__ float2 Pn[NN];
    __shared__ float2 Vl[NN];
    __shared__ float Pm0[NN], Pm1[NN];

    // ---------------- setup (once per block) ----------------
    if (t < 512) {
        float v = enc[b * (NS * NE) + t];      // coalesced
        if (t & 1) e1_l[t >> 1] = v; else e0_l[t >> 1] = v;
    }
    if (t < NN * NN) {
        const int mi = t >> 4, mj = t & 15;
        const float w = (mi == 0) ? (1.0f / NN) : (2.0f / NN);
        Ml[t] = w * __cosf((float)(mi * (2 * mj + 1)) * (PI_F / (2 * NN)));
    }
    __syncthreads();

    // w1sum rows and w2term rows: 16 rows per wave (DPP reductions).
    for (int r = 0; r < 16; ++r) {
        const int s = wave * 16 + r;
        float p = W1w[s * NS + lane]       + W1w[s * NS + lane + 64]
                + W1w[s * NS + lane + 128] + W1w[s * NS + lane + 192];
        p = red_wave64(p);
        if (lane == 63) g2_l[s] = p * (2.0f * L2E);
        float qq = 0.0f;
        #pragma unroll
        for (int kk = 0; kk < 8; ++kk) {
            const int c = lane + kk * 64;
            const float ev = (c & 1) ? e1_l[c >> 1] : e0_l[c >> 1];
            qq = fmaf(ev, W2w[s * (2 * NS) + c], qq);
        }
        qq = red_wave64(qq);
        if (lane == 63) A2_l[s] = (qq + W2b[s] + W1b[s]) * (2.0f * L2E);
    }
    __syncthreads();

    // One-time node softmax: F(y_j), node j = wave (16 nodes / 16 waves).
    {
        const float y  = __cosf((float)(2 * wave + 1) * (PI_F / (2 * NN)));
        const float C2 = -2.0f * L2E;
        float l = 0.0f, p0 = 0.0f, p1 = 0.0f;
        #pragma unroll
        for (int k = 0; k < 4; ++k) {
            const int s = k * 64 + lane;
            const float m1 = fmaf(y, g2_l[s], A2_l[s]);
            const float u  = __builtin_amdgcn_exp2f(m1);
            const float rc = __builtin_amdgcn_rcpf(u + 1.0f);
            const float e  = __builtin_amdgcn_exp2f(rc * C2);
            l += e;
            p0 = fmaf(e, e0_l[s], p0);
            p1 = fmaf(e, e1_l[s], p1);
        }
        l = red_wave64(l); p0 = red_wave64(p0); p1 = red_wave64(p1);
        if (lane == 63) {
            const float rl = __builtin_amdgcn_rcpf(l);
            Pn[wave] = make_float2(p0 * rl, p1 * rl);
        }
    }
    __syncthreads();

    // DCT collapse: V[i] = sum_j M[i][j]*Pn[j], 1/ND folded in.
    if (t < NN) {
        float v0 = 0.0f, v1 = 0.0f;
        #pragma unroll
        for (int j = 0; j < NN; ++j) {
            v0 = fmaf(Ml[t * NN + j], Pn[j].x, v0);
            v1 = fmaf(Ml[t * NN + j], Pn[j].y, v1);
        }
        Vl[t] = make_float2(v0 * (1.0f / ND), v1 * (1.0f / ND));
    }

    // W_hh slices for rows g+128j, K range [16q,16q+16) -> 8 packed f16x2 each.
    f16x2 wr16[4][8];
    float wi0_[4], wi1_[4], bb_[4];
    #pragma unroll
    for (int j = 0; j < 4; ++j) {
        const int r = g + 128 * j;
        const vf4* W4 = reinterpret_cast<const vf4*>(Whh + r * ND + q * 16);
        #pragma unroll
        for (int i = 0; i < 4; ++i) {
            const vf4 w = W4[i];
            wr16[j][2 * i + 0] = f16x2{(_Float16)w.x, (_Float16)w.y};
            wr16[j][2 * i + 1] = f16x2{(_Float16)w.z, (_Float16)w.w};
        }
        wi0_[j] = Wih[r * 2 + 0];
        wi1_[j] = Wih[r * 2 + 1];
        bb_[j]  = bih[r] + bhh[r];
    }

    // zero-init ring slot 31 (input of step 0) in both rings
    if (t < ND) {
        hist[31 * SLOT + 36 * (t >> 5) + (t & 31)] = 0.0f;
        hist16[31 * SLOTH + 24 * (t >> 4) + (t & 15)] = (_Float16)0.0f;
    }
    float h_reg = 0.0f, c_reg = 0.0f;
    __syncthreads();                   // Vl visible

    // Chebyshev -> monomial: Pm[m] = sum_k V[k] * CT[k][m].
    if (t < NN) {
        float s0 = 0.0f, s1 = 0.0f;
        #pragma unroll
        for (int k = 0; k < NN; ++k) {
            s0 = fmaf(Vl[k].x, CT[k][t], s0);
            s1 = fmaf(Vl[k].y, CT[k][t], s1);
        }
        Pm0[t] = s0; Pm1[t] = s1;
    }
    __syncthreads();                   // Pm visible

    // Per-lane residue-class coeffs: G_e(h) = sum_q h^q (c_q + c_{q+8} h^8).
    const float Qa0 = Pm0[q],     Qa1 = Pm1[q];
    const float Qb0 = Pm0[q + 8], Qb1 = Pm1[q + 8];

    // phaseG: octet-split monomial eval; red_oct reassembles G(h), then
    // mirror/bcast-reduce over the wave's 8 octets. lane63 writes partial.
    auto phaseG = [&](float h, int pw) {
        const float h2 = h * h;
        const float h4 = h2 * h2;
        const float h8 = h4 * h4;
        const float s1 = qb0 ? h  : 1.0f;
        const float s2 = qb1 ? h2 : 1.0f;
        const float s4 = qb2 ? h4 : 1.0f;
        const float hq = s1 * s2 * s4;
        float a0 = fmaf(Qb0, h8, Qa0) * hq;
        float a1 = fmaf(Qb1, h8, Qa1) * hq;
        a0 = red_oct(a0);      a1 = red_oct(a1);       // reassemble G(h_g)
        a0 = red_oct2wave(a0); a1 = red_oct2wave(a1);  // sum the wave's 8 g
        if (lane == 63) {
            xwbuf[pw][2 * wave + 0] = a0;
            xwbuf[pw][2 * wave + 1] = a1;
        }
    };

    phaseG(0.0f, 0);       // x for step 0 (h = 0)
    __syncthreads();

    // ---------------- the recurrence (ONE barrier per step) ----------------
    for (int step = 0; step < NS; ++step) {
        const int pr = step & 1;
        const int rs = (step + RING - 1) & (RING - 1);   // slot holding h(step-1)
        const int ws = step & (RING - 1);                // slot for h(step)

        // Front-load all LDS reads so their latency overlaps the chunk store.
        float2 xv = *reinterpret_cast<const float2*>(&xwbuf[pr][2 * (lane & 15)]);
        const int4* hb = reinterpret_cast<const int4*>(&hist16[rs * SLOTH + q * 24]);
        int hw[8];
        #pragma unroll
        for (int i = 0; i < 2; ++i) {
            const int4 v = hb[i];                // b128, 8 bases on disjoint banks
            hw[4 * i + 0] = v.x; hw[4 * i + 1] = v.y;
            hw[4 * i + 2] = v.z; hw[4 * i + 3] = v.w;
        }

        // Chunk store (every 16 steps, at step TOP): steps step-16..step-1.
        if ((step & 15) == 0 && step > 0) {
            const int sb = (step - 16) & (RING - 1);
            const int k  = t >> 6;             // which of the 16 steps
            const int l  = t & 63;             // 128 floats / 64 lanes, float2 each
            const float2 v = *reinterpret_cast<const float2*>(
                &hist[(sb + k) * SLOT + 36 * (l >> 4) + ((2 * l) & 31)]);
            *reinterpret_cast<float2*>(
                &out[(size_t)(step - 16 + k) * (NB * ND) + b * ND + 2 * l]) = v;
        }

        float x0 = red_row16(xv.x);
        float x1 = red_row16(xv.y);

        // Gate dots over this thread's 16-element h slice: 8 fdot2 per row,
        // 2 independent accumulator chains per row.
        float d0a = 0.f, d0b = 0.f, d1a = 0.f, d1b = 0.f;
        float d2a = 0.f, d2b = 0.f, d3a = 0.f, d3b = 0.f;
        #pragma unroll
        for (int i = 0; i < 4; ++i) {
            const f16x2 ha  = __builtin_bit_cast(f16x2, hw[2 * i + 0]);
            const f16x2 hbv = __builtin_bit_cast(f16x2, hw[2 * i + 1]);
            d0a = __builtin_amdgcn_fdot2(wr16[0][2 * i + 0], ha,  d0a, false);
            d0b = __builtin_amdgcn_fdot2(wr16[0][2 * i + 1], hbv, d0b, false);
            d1a = __builtin_amdgcn_fdot2(wr16[1][2 * i + 0], ha,  d1a, false);
            d1b = __builtin_amdgcn_fdot2(wr16[1][2 * i + 1], hbv, d1b, false);
            d2a = __builtin_amdgcn_fdot2(wr16[2][2 * i + 0], ha,  d2a, false);
            d2b = __builtin_amdgcn_fdot2(wr16[2][2 * i + 1], hbv, d2b, false);
            d3a = __builtin_amdgcn_fdot2(wr16[3][2 * i + 0], ha,  d3a, false);
            d3b = __builtin_amdgcn_fdot2(wr16[3][2 * i + 1], hbv, d3b, false);
        }
        float d0 = d0a + d0b, d1 = d1a + d1b;
        float d2 = d2a + d2b, d3 = d3a + d3b;
        d0 = red_oct(d0);  d1 = red_oct(d1);             // sum the 8 K-slices
        d2 = red_oct(d2);  d3 = red_oct(d3);

        const float gi = d0 + fmaf(x0, wi0_[0], fmaf(x1, wi1_[0], bb_[0]));
        const float gf = d1 + fmaf(x0, wi0_[1], fmaf(x1, wi1_[1], bb_[1]));
        const float gg = d2 + fmaf(x0, wi0_[2], fmaf(x1, wi1_[2], bb_[2]));
        const float go = d3 + fmaf(x0, wi0_[3], fmaf(x1, wi1_[3], bb_[3]));

        // LSTM pointwise (redundant on the 8 octet lanes -> h stays in-register)
        const float si = __builtin_amdgcn_rcpf(1.0f + __builtin_amdgcn_exp2f(-L2E * gi));
        const float sf = __builtin_amdgcn_rcpf(1.0f + __builtin_amdgcn_exp2f(-L2E * gf));
        const float so = __builtin_amdgcn_rcpf(1.0f + __builtin_amdgcn_exp2f(-L2E * go));
        const float tg = 1.0f - 2.0f * __builtin_amdgcn_rcpf(__builtin_amdgcn_exp2f(2.0f * L2E * gg) + 1.0f);
        c_reg = sf * c_reg + si * tg;
        const float tc2 = 1.0f - 2.0f * __builtin_amdgcn_rcpf(__builtin_amdgcn_exp2f(2.0f * L2E * c_reg) + 1.0f);
        h_reg = so * tc2;

        if (q == 0) {
            hist[ws * SLOT + 36 * (g >> 5) + (g & 31)] = h_reg;
            hist16[ws * SLOTH + 24 * (g >> 4) + (g & 15)] = (_Float16)h_reg;
        }
        phaseG(h_reg, pr ^ 1);                           // x for step k+1

        __syncthreads();
    }

    // Tail: store the final chunk (steps 240..255, ring slots 16..31).
    {
        const int k = t >> 6;
        const int l = t & 63;
        const float2 v = *reinterpret_cast<const float2*>(
            &hist[(16 + k) * SLOT + 36 * (l >> 4) + ((2 * l) & 31)]);
        *reinterpret_cast<float2*>(
            &out[(size_t)(240 + k) * (NB * ND) + b * ND + 2 * l]) = v;
    }
}

extern "C" void kernel_launch(void* const* d_in, const int* in_sizes, int n_in,
                              void* d_out, int out_size, void* d_ws, size_t ws_size,
                              hipStream_t stream) {
    const float* enc = (const float*)d_in[0];
    const float* W1w = (const float*)d_in[1];
    const float* W1b = (const float*)d_in[2];
    const float* W2w = (const float*)d_in[3];
    const float* W2b = (const float*)d_in[4];
    const float* Wih = (const float*)d_in[5];
    const float* Whh = (const float*)d_in[6];
    const float* bih = (const float*)d_in[7];
    const float* bhh = (const float*)d_in[8];
    attn_lstm_decoder<<<NB, NT, 0, stream>>>(enc, W1w, W1b, W2w, W2b,
                                             Wih, Whh, bih, bhh, (float*)d_out);
}